// Round 8
// baseline (2345.034 us; speedup 1.0000x reference)
//
#include <hip/hip_runtime.h>
#include <hip/hip_bf16.h>
#include <math.h>

// Problem constants
#define NN      1500
#define NEE     1200
#define NPAD    1536
#define BATCH   96
#define NSTEP   60
#define PI_F    3.14159265358979323846f

// geometry: 192 WGs = 96 i-tiles (16) x 2 batch-halves (48); 1024 thr / 16 waves
#define NWG     192
#define GRPWG   96             // WGs per batch-half group (sync domain)
#define NTHR    1024
#define WAVES   16
#define KSLW    (NPAD / WAVES) // 96 = 3 MFMA k-iters of 32
#define BH      48             // batch-half size
#define MFR     3              // m fragments per wave (48/16)

// LDS reduce: 16 slots x [2 outs][16 i][49 pad-b] f32
#define BP      49
#define SLOTF   (2 * 16 * BP)            // 1568 floats
#define LDS_BYTES (WAVES * SLOTF * 4)    // 100352 B (dynamic) -> 1 WG/CU

typedef __attribute__((ext_vector_type(8))) short short8b;  // 8 bf16
typedef __attribute__((ext_vector_type(4))) float f32x4;    // MFMA acc

// ---------------- bf16 split helpers ----------------------------------------

__device__ __forceinline__ ushort bf16_rn(float x) {
    unsigned u = __float_as_uint(x);
    unsigned r = (u + 0x7FFFu + ((u >> 16) & 1u)) >> 16;
    return (ushort)r;
}
__device__ __forceinline__ float bf16f(ushort h) {
    return __uint_as_float(((unsigned)h) << 16);
}

// coherent (agent-scope, sc1 -> bypasses non-coherent XCD L2) plane access
__device__ __forceinline__ short8b load_pair8(const ushort* plane, size_t elem) {
    uint* p = (uint*)(plane + elem);     // elem is even -> 4B aligned
    union { uint u[4]; short8b v; } x;
    x.u[0] = __hip_atomic_load(p + 0, __ATOMIC_RELAXED, __HIP_MEMORY_SCOPE_AGENT);
    x.u[1] = __hip_atomic_load(p + 1, __ATOMIC_RELAXED, __HIP_MEMORY_SCOPE_AGENT);
    x.u[2] = __hip_atomic_load(p + 2, __ATOMIC_RELAXED, __HIP_MEMORY_SCOPE_AGENT);
    x.u[3] = __hip_atomic_load(p + 3, __ATOMIC_RELAXED, __HIP_MEMORY_SCOPE_AGENT);
    return x.v;
}

// ---------------- phi (Ricciardi LIF transfer) ------------------------------

__device__ __forceinline__ float f_ricci(float x) {
    float z = x / (1.0f + x);
    float t = -z;
    float p = 0.14805913578876898f;
    p = p * t + 0.64290613877355551f;
    p = p * t + 1.0616084849547165f;
    p = p * t + 0.93524391761244940f;
    p = p * t + 0.62718906618071668f;
    p = p * t + 0.32171431660633076f;
    p = p * t + 0.32056016125642045f;
    p = p * t + 0.77373949685442023f;
    p = p * t + 0.22757881388024176f;
    p = p * t;
    return logf(2.0f * x + 1.0f) + p;
}

__device__ __forceinline__ float g_ricci(float x) {
    float z = x / (2.0f + x);
    float num = z * (3.5441754117462949f + z * (-7.0529131065835378f + z * (-56.532378057580381f
        + z * (279.56761105465944f + z * (-520.37554849441472f + z * (456.58245777026514f
        + z * (-155.73340457809226f)))))));
    float den = 1.0f + z * (-4.1357968834226053f + z * (-7.2984226138266743f + z * (98.656602235468327f
        + z * (-334.20436223415163f + z * (601.08633903294185f + z * (-599.58577549598340f
        + z * (277.18420330693891f + z * (-16.445022798669722f))))))));
    return num / den;
}

__device__ __forceinline__ float phi_lif(float mu, float sig, float tau, float tau_ref) {
    float xp = mu / sig;
    float xm = (mu - 20.0f) / sig;
    float r0;
    if (xm > 0.0f) {
        r0 = 1.0f / (f_ricci(xp) - f_ricci(xm));
    } else if (xp > 0.0f) {
        r0 = 1.0f / (f_ricci(xp) + expf(xm * xm) * g_ricci(-xm));
    } else {
        float a = g_ricci(-xm) - expf(xp * xp - xm * xm) * g_ricci(-xp);
        r0 = expf(-xm * xm - logf(a));
    }
    r0 = fmaxf(r0, 1e-30f);
    return 1.0f / (tau_ref + tau / r0);
}

__device__ __forceinline__ float pref_of(int n) {
    const float stepE = 179.99f / 1200.0f;
    const float stepI = 179.99f / 300.0f;
    return (n < NEE) ? (float)n * stepE : (float)(n - NEE) * stepI;
}

// ---------------- kernel 1: build bf16-split weight planes [i][k] -----------

__global__ __launch_bounds__(256) void k_weights(const float* __restrict__ hyp,
        const float* __restrict__ rand_mat,
        ushort* __restrict__ Whi, ushort* __restrict__ Wlo,
        ushort* __restrict__ W2hi, ushort* __restrict__ W2lo) {
    int k = blockIdx.x * 256 + threadIdx.x;   // source neuron (contiguous)
    int i = blockIdx.y;                        // dest neuron
    size_t idx = (size_t)i * NPAD + k;
    if (i >= NN || k >= NN) {
        Whi[idx] = 0; Wlo[idx] = 0; W2hi[idx] = 0; W2lo[idx] = 0;
        return;
    }
    float diff = fabsf(pref_of(i) - pref_of(k));
    int conn = (i >= NEE ? 1 : 0) + 2 * (k >= NEE ? 1 : 0);
    float J  = hyp[conn];
    float P  = hyp[4 + conn];
    float Wp = hyp[8 + conn];
    float dn = 4.0f * (PI_F / 180.0f * Wp) * (PI_F / 180.0f * Wp);
    float z = expf((cosf(2.0f * PI_F / 180.0f * diff) - 1.0f) / dn);
    float x = 32.0f * (P * z - rand_mat[(size_t)i * NN + k]);
    float w = J / (1.0f + expf(-x));
    float w2 = w * w;
    ushort h = bf16_rn(w);
    Whi[idx] = h;  Wlo[idx] = bf16_rn(w - bf16f(h));
    ushort h2 = bf16_rn(w2);
    W2hi[idx] = h2; W2lo[idx] = bf16_rn(w2 - bf16f(h2));
}

// ---------------- kernel 2: zero initial planes + barrier counters ----------

__global__ __launch_bounds__(256) void k_init(ushort* __restrict__ rhiA,
                                              ushort* __restrict__ rloA,
                                              uint* __restrict__ cnt) {
    int i = blockIdx.x * 256 + threadIdx.x;
    int b = blockIdx.y;
    size_t idx = (size_t)b * NPAD + i;
    rhiA[idx] = 0;
    rloA[idx] = 0;
    if (blockIdx.x == 0 && blockIdx.y == 0 && threadIdx.x < 2) cnt[threadIdx.x] = 0;
}

// ---------------- kernel 3: all 60 steps, cooperative, fence-free -----------
// Two independent 96-WG groups (batch halves). Per step: MFMA over K-split
// (R7 decomposition, identical numerics) -> one-barrier LDS reduce -> phi +
// Euler (rate/mean in registers) -> coherent (agent) plane stores -> leader
// atomic-counter barrier. W planes use normal cached loads (L2-resident all
// 60 steps); rate planes use agent-scope sc1 loads/stores (cross-XCD safe).

__global__ __launch_bounds__(NTHR) void k_coop(
        const ushort* __restrict__ Whi, const ushort* __restrict__ Wlo,
        const ushort* __restrict__ W2hi, const ushort* __restrict__ W2lo,
        ushort* __restrict__ rhiA, ushort* __restrict__ rloA,
        ushort* __restrict__ rhiB, ushort* __restrict__ rloB,
        uint* __restrict__ cnt, float* __restrict__ out)
{
    extern __shared__ float sm[];
    const int tid  = threadIdx.x;
    const int wave = tid >> 6;
    const int lane = tid & 63;
    const int lr   = lane & 15;
    const int lq   = lane >> 4;
    const int bx   = blockIdx.x;
    const int it   = bx % 96;          // bx, bx+96 are 96 apart -> same XCD (96%8==0)
    const int bhf  = bx / 96;          // batch half = sync group
    const int i0   = it * 16;
    const int b0   = bhf * BH;
    const int kb   = wave * KSLW;

    // ---- per-thread update element (matches R7 mapping), state in registers
    const int c  = tid & 15;           // i within tile
    const int bb = tid >> 4;           // b within half (valid when tid < 768)
    const int ig = i0 + c;
    const int gb = b0 + bb;
    const size_t gx = (size_t)gb * NPAD + ig;
    const bool upd = (tid < BH * 16);

    const float contrasts[8] = {0.0f, 0.0432773f, 0.103411f, 0.186966f,
                                0.303066f, 0.464386f, 0.68854f, 1.0f};
    const float dnff = 4.0f * (PI_F / 180.0f * 30.0f) * (PI_F / 180.0f * 30.0f);
    float mean0 = 0.0f;
    if (upd && ig < NN) {
        float dth = 15.0f * (float)(gb % 12) - pref_of(ig);
        mean0 = contrasts[gb / 12] * 20.0f *
                expf((cosf(2.0f * PI_F / 180.0f * dth) - 1.0f) / dnff);
    }
    float rr = 0.0f;

    const size_t bof = (size_t)(i0 + lr) * NPAD + kb + lq * 8;

    for (int s = 0; s < NSTEP; s++) {
        const ushort* rin_hi = (s & 1) ? rhiB : rhiA;
        const ushort* rin_lo = (s & 1) ? rloB : rloA;
        ushort* rout_hi = (s & 1) ? rhiA : rhiB;
        ushort* rout_lo = (s & 1) ? rloA : rloB;

        f32x4 acc1[MFR], acc2[MFR];
#pragma unroll
        for (int m = 0; m < MFR; m++) {
            acc1[m] = (f32x4){0.0f, 0.0f, 0.0f, 0.0f};
            acc2[m] = (f32x4){0.0f, 0.0f, 0.0f, 0.0f};
        }

#pragma unroll
        for (int kk = 0; kk < KSLW / 32; kk++) {
            const int ko = kk * 32;
            short8b wh  = *(const short8b*)(Whi  + bof + ko);   // cached, L2-hot
            short8b wl  = *(const short8b*)(Wlo  + bof + ko);
            short8b w2h = *(const short8b*)(W2hi + bof + ko);
            short8b w2l = *(const short8b*)(W2lo + bof + ko);
#pragma unroll
            for (int m = 0; m < MFR; m++) {
                const size_t aof = (size_t)(b0 + m * 16 + lr) * NPAD + kb + lq * 8 + ko;
                short8b ah = load_pair8(rin_hi, aof);           // coherent sc1
                short8b al = load_pair8(rin_lo, aof);
                // identical pass set to rounds 4/5/7 (numerics held constant)
                acc1[m] = __builtin_amdgcn_mfma_f32_16x16x32_bf16(ah, wh,  acc1[m], 0, 0, 0);
                acc1[m] = __builtin_amdgcn_mfma_f32_16x16x32_bf16(ah, wl,  acc1[m], 0, 0, 0);
                acc1[m] = __builtin_amdgcn_mfma_f32_16x16x32_bf16(al, wh,  acc1[m], 0, 0, 0);
                acc2[m] = __builtin_amdgcn_mfma_f32_16x16x32_bf16(ah, w2h, acc2[m], 0, 0, 0);
                acc2[m] = __builtin_amdgcn_mfma_f32_16x16x32_bf16(ah, w2l, acc2[m], 0, 0, 0);
                acc2[m] = __builtin_amdgcn_mfma_f32_16x16x32_bf16(al, w2h, acc2[m], 0, 0, 0);
            }
        }

        // ---- dump accs to own slot; C/D map: col(i)=lr, row(b in frag)=4*lq+r
        {
            float* sp = sm + wave * SLOTF;
#pragma unroll
            for (int m = 0; m < MFR; m++) {
                float* p1 = sp + lr * BP + m * 16 + 4 * lq;
                float* p2 = p1 + 16 * BP;
                *(f32x4*)p1 = acc1[m];
                *(f32x4*)p2 = acc2[m];
            }
        }
        __syncthreads();

        // ---- sum 16 slots + phi + Euler; pack pairs; coherent stores --------
        if (upd) {
            float rn = 0.0f;
            if (ig < NN) {
                float u1 = 0.0f, u2 = 0.0f;
#pragma unroll
                for (int w = 0; w < WAVES; w++) {
                    u1 += sm[w * SLOTF + c * BP + bb];
                    u2 += sm[w * SLOTF + (16 + c) * BP + bb];
                }
                float mu = 0.01f * u1 + mean0;
                float sg = sqrtf(0.01f * u2 + 25.0f);      // SIG_EXT^2 = 25
                float tr = (ig < NEE) ? 0.005f : 0.001f;
                float Ti = (ig < NEE) ? 100.0f : 200.0f;
                float ph = phi_lif(mu, sg, 0.01f, tr);
                rr = rr + 1e-3f * Ti * (ph - rr);
                rn = rr;
                if (s == NSTEP - 1) out[(size_t)ig * BATCH + gb] = rn;
            }
            int hh = (int)bf16_rn(rn);
            int ll = (int)bf16_rn(rn - bf16f((ushort)hh));
            int hN = __shfl_down(hh, 1);   // neighbor c+1 (same wave, no wrap for even c)
            int lN = __shfl_down(ll, 1);
            if ((c & 1) == 0) {
                uint hp = (uint)hh | ((uint)hN << 16);
                uint lp = (uint)ll | ((uint)lN << 16);
                __hip_atomic_store((uint*)(rout_hi + gx), hp,
                                   __ATOMIC_RELAXED, __HIP_MEMORY_SCOPE_AGENT);
                __hip_atomic_store((uint*)(rout_lo + gx), lp,
                                   __ATOMIC_RELAXED, __HIP_MEMORY_SCOPE_AGENT);
            }
        }

        // ---- leader-counter group barrier (no fences; sc1 stores already
        //      at coherence point once vmcnt drains) -------------------------
        asm volatile("s_waitcnt vmcnt(0)" ::: "memory");
        __syncthreads();                    // all waves' stores drained
        if (tid == 0) {
            __hip_atomic_fetch_add(cnt + bhf, 1u,
                                   __ATOMIC_RELAXED, __HIP_MEMORY_SCOPE_AGENT);
            const uint target = (uint)(s + 1) * GRPWG;
            while (__hip_atomic_load(cnt + bhf,
                       __ATOMIC_RELAXED, __HIP_MEMORY_SCOPE_AGENT) < target)
                __builtin_amdgcn_s_sleep(2);
        }
        __syncthreads();                    // release whole WG into next step
    }
}

// ---------------- launch ----------------------------------------------------

extern "C" void kernel_launch(void* const* d_in, const int* in_sizes, int n_in,
                              void* d_out, int out_size, void* d_ws, size_t ws_size,
                              hipStream_t stream) {
    const float* hyp      = (const float*)d_in[0];   // [3][4]
    const float* rand_mat = (const float*)d_in[1];   // [1500][1500]
    float* out            = (float*)d_out;           // [1500][8][12]

    char* p = (char*)d_ws;
    ushort* Whi  = (ushort*)p; p += (size_t)NPAD * NPAD * 2;
    ushort* Wlo  = (ushort*)p; p += (size_t)NPAD * NPAD * 2;
    ushort* W2hi = (ushort*)p; p += (size_t)NPAD * NPAD * 2;
    ushort* W2lo = (ushort*)p; p += (size_t)NPAD * NPAD * 2;
    ushort* rhiA = (ushort*)p; p += (size_t)BATCH * NPAD * 2;
    ushort* rloA = (ushort*)p; p += (size_t)BATCH * NPAD * 2;
    ushort* rhiB = (ushort*)p; p += (size_t)BATCH * NPAD * 2;
    ushort* rloB = (ushort*)p; p += (size_t)BATCH * NPAD * 2;
    uint*   cnt  = (uint*)p;   p += 256;

    hipFuncSetAttribute((const void*)k_coop,
                        hipFuncAttributeMaxDynamicSharedMemorySize, LDS_BYTES);

    k_weights<<<dim3(NPAD / 256, NPAD), 256, 0, stream>>>(hyp, rand_mat,
                                                          Whi, Wlo, W2hi, W2lo);
    k_init<<<dim3(NPAD / 256, BATCH), 256, 0, stream>>>(rhiA, rloA, cnt);

    void* args[] = {(void*)&Whi, (void*)&Wlo, (void*)&W2hi, (void*)&W2lo,
                    (void*)&rhiA, (void*)&rloA, (void*)&rhiB, (void*)&rloB,
                    (void*)&cnt, (void*)&out};
    hipLaunchCooperativeKernel((const void*)k_coop, dim3(NWG), dim3(NTHR),
                               args, LDS_BYTES, stream);
}

// Round 9
// 1002.651 us; speedup vs baseline: 2.3388x; 2.3388x over previous
//
#include <hip/hip_runtime.h>
#include <hip/hip_bf16.h>
#include <math.h>

// Problem constants
#define NN      1500
#define NEE     1200
#define NPAD    1536
#define BATCH   96
#define NSTEP   60
#define PI_F    3.14159265358979323846f

// geometry: 192 WGs = 96 i-tiles (16) x 2 batch-halves (48); 1024 thr / 16 waves
#define NWG     192
#define GRPWG   96             // WGs per batch-half group (sync domain)
#define SUBWG   12             // WGs per sub-barrier (96/8)
#define NTHR    1024
#define WAVES   16
#define KSLW    (NPAD / WAVES) // 96 = 3 MFMA k-iters of 32
#define BH      48             // batch-half size
#define MFR     3              // m fragments per wave (48/16)

// LDS reduce: 16 slots x [2 outs][16 i][49 pad-b] f32
#define BP      49
#define SLOTF   (2 * 16 * BP)            // 1568 floats
#define LDS_BYTES (WAVES * SLOTF * 4)    // 100352 B (dynamic) -> 1 WG/CU

typedef __attribute__((ext_vector_type(8))) short short8b;  // 8 bf16
typedef __attribute__((ext_vector_type(4))) float f32x4;    // MFMA acc

// ---------------- bf16 split helpers ----------------------------------------

__device__ __forceinline__ ushort bf16_rn(float x) {
    unsigned u = __float_as_uint(x);
    unsigned r = (u + 0x7FFFu + ((u >> 16) & 1u)) >> 16;
    return (ushort)r;
}
__device__ __forceinline__ float bf16f(ushort h) {
    return __uint_as_float(((unsigned)h) << 16);
}

// coherent 16B load: sc0 sc1 -> bypasses CU L1 + non-coherent XCD L2, served
// at the L3 coherence point; coalesces like a normal global_load_dwordx4.
__device__ __forceinline__ short8b load16_sc1(const ushort* p) {
    short8b r;
    asm volatile("global_load_dwordx4 %0, %1, off sc0 sc1"
                 : "=v"(r) : "v"((unsigned long long)(uintptr_t)p));
    return r;
}

// ---------------- phi (Ricciardi LIF transfer) ------------------------------

__device__ __forceinline__ float f_ricci(float x) {
    float z = x / (1.0f + x);
    float t = -z;
    float p = 0.14805913578876898f;
    p = p * t + 0.64290613877355551f;
    p = p * t + 1.0616084849547165f;
    p = p * t + 0.93524391761244940f;
    p = p * t + 0.62718906618071668f;
    p = p * t + 0.32171431660633076f;
    p = p * t + 0.32056016125642045f;
    p = p * t + 0.77373949685442023f;
    p = p * t + 0.22757881388024176f;
    p = p * t;
    return logf(2.0f * x + 1.0f) + p;
}

__device__ __forceinline__ float g_ricci(float x) {
    float z = x / (2.0f + x);
    float num = z * (3.5441754117462949f + z * (-7.0529131065835378f + z * (-56.532378057580381f
        + z * (279.56761105465944f + z * (-520.37554849441472f + z * (456.58245777026514f
        + z * (-155.73340457809226f)))))));
    float den = 1.0f + z * (-4.1357968834226053f + z * (-7.2984226138266743f + z * (98.656602235468327f
        + z * (-334.20436223415163f + z * (601.08633903294185f + z * (-599.58577549598340f
        + z * (277.18420330693891f + z * (-16.445022798669722f))))))));
    return num / den;
}

__device__ __forceinline__ float phi_lif(float mu, float sig, float tau, float tau_ref) {
    float xp = mu / sig;
    float xm = (mu - 20.0f) / sig;
    float r0;
    if (xm > 0.0f) {
        r0 = 1.0f / (f_ricci(xp) - f_ricci(xm));
    } else if (xp > 0.0f) {
        r0 = 1.0f / (f_ricci(xp) + expf(xm * xm) * g_ricci(-xm));
    } else {
        float a = g_ricci(-xm) - expf(xp * xp - xm * xm) * g_ricci(-xp);
        r0 = expf(-xm * xm - logf(a));
    }
    r0 = fmaxf(r0, 1e-30f);
    return 1.0f / (tau_ref + tau / r0);
}

__device__ __forceinline__ float pref_of(int n) {
    const float stepE = 179.99f / 1200.0f;
    const float stepI = 179.99f / 300.0f;
    return (n < NEE) ? (float)n * stepE : (float)(n - NEE) * stepI;
}

// ---------------- kernel 1: build bf16-split weight planes [i][k] -----------

__global__ __launch_bounds__(256) void k_weights(const float* __restrict__ hyp,
        const float* __restrict__ rand_mat,
        ushort* __restrict__ Whi, ushort* __restrict__ Wlo,
        ushort* __restrict__ W2hi, ushort* __restrict__ W2lo) {
    int k = blockIdx.x * 256 + threadIdx.x;   // source neuron (contiguous)
    int i = blockIdx.y;                        // dest neuron
    size_t idx = (size_t)i * NPAD + k;
    if (i >= NN || k >= NN) {
        Whi[idx] = 0; Wlo[idx] = 0; W2hi[idx] = 0; W2lo[idx] = 0;
        return;
    }
    float diff = fabsf(pref_of(i) - pref_of(k));
    int conn = (i >= NEE ? 1 : 0) + 2 * (k >= NEE ? 1 : 0);
    float J  = hyp[conn];
    float P  = hyp[4 + conn];
    float Wp = hyp[8 + conn];
    float dn = 4.0f * (PI_F / 180.0f * Wp) * (PI_F / 180.0f * Wp);
    float z = expf((cosf(2.0f * PI_F / 180.0f * diff) - 1.0f) / dn);
    float x = 32.0f * (P * z - rand_mat[(size_t)i * NN + k]);
    float w = J / (1.0f + expf(-x));
    float w2 = w * w;
    ushort h = bf16_rn(w);
    Whi[idx] = h;  Wlo[idx] = bf16_rn(w - bf16f(h));
    ushort h2 = bf16_rn(w2);
    W2hi[idx] = h2; W2lo[idx] = bf16_rn(w2 - bf16f(h2));
}

// ---------------- kernel 2: zero initial planes + barrier counters ----------

__global__ __launch_bounds__(256) void k_init(ushort* __restrict__ rhiA,
                                              ushort* __restrict__ rloA,
                                              uint* __restrict__ cnt) {
    int i = blockIdx.x * 256 + threadIdx.x;
    int b = blockIdx.y;
    size_t idx = (size_t)b * NPAD + i;
    rhiA[idx] = 0;
    rloA[idx] = 0;
    if (blockIdx.x == 0 && blockIdx.y == 0) {
        for (int t = threadIdx.x; t < 1024; t += 256) cnt[t] = 0;
    }
}

// ---------------- kernel 3: all 60 steps, cooperative, fence-free -----------
// Two independent 96-WG groups (batch halves). Per step: MFMA over K-split
// (R7 decomposition, identical numerics) -> one-barrier LDS reduce -> phi +
// Euler (rate/mean in registers) -> coherent plane stores -> hierarchical
// atomic barrier (8 sub-counters -> master -> broadcast flag).
// W planes: normal cached loads (L2-resident across all 60 steps).
// Rate planes: sc1 16B loads / 4B agent stores (cross-XCD coherent).

__global__ __launch_bounds__(NTHR) void k_coop(
        const ushort* __restrict__ Whi, const ushort* __restrict__ Wlo,
        const ushort* __restrict__ W2hi, const ushort* __restrict__ W2lo,
        ushort* __restrict__ rhiA, ushort* __restrict__ rloA,
        ushort* __restrict__ rhiB, ushort* __restrict__ rloB,
        uint* __restrict__ cnt, float* __restrict__ out)
{
    extern __shared__ float sm[];
    const int tid  = threadIdx.x;
    const int wave = tid >> 6;
    const int lane = tid & 63;
    const int lr   = lane & 15;
    const int lq   = lane >> 4;
    const int bx   = blockIdx.x;
    const int it   = bx % 96;          // bx, bx+96 are 96 apart -> same XCD (96%8==0)
    const int bhf  = bx / 96;          // batch half = sync group
    const int i0   = it * 16;
    const int b0   = bhf * BH;
    const int kb   = wave * KSLW;

    // ---- per-thread update element (matches R7 mapping), state in registers
    const int c  = tid & 15;           // i within tile
    const int bb = tid >> 4;           // b within half (valid when tid < 768)
    const int ig = i0 + c;
    const int gb = b0 + bb;
    const size_t gx = (size_t)gb * NPAD + ig;
    const bool upd = (tid < BH * 16);

    const float contrasts[8] = {0.0f, 0.0432773f, 0.103411f, 0.186966f,
                                0.303066f, 0.464386f, 0.68854f, 1.0f};
    const float dnff = 4.0f * (PI_F / 180.0f * 30.0f) * (PI_F / 180.0f * 30.0f);
    float mean0 = 0.0f;
    if (upd && ig < NN) {
        float dth = 15.0f * (float)(gb % 12) - pref_of(ig);
        mean0 = contrasts[gb / 12] * 20.0f *
                expf((cosf(2.0f * PI_F / 180.0f * dth) - 1.0f) / dnff);
    }
    float rr = 0.0f;

    const size_t bof = (size_t)(i0 + lr) * NPAD + kb + lq * 8;
    // per-m A base offsets (constant across steps)
    size_t aofm[MFR];
#pragma unroll
    for (int m = 0; m < MFR; m++)
        aofm[m] = (size_t)(b0 + m * 16 + lr) * NPAD + kb + lq * 8;

    for (int s = 0; s < NSTEP; s++) {
        const ushort* rin_hi = (s & 1) ? rhiB : rhiA;
        const ushort* rin_lo = (s & 1) ? rloB : rloA;
        ushort* rout_hi = (s & 1) ? rhiA : rhiB;
        ushort* rout_lo = (s & 1) ? rloA : rloB;

        f32x4 acc1[MFR], acc2[MFR];
#pragma unroll
        for (int m = 0; m < MFR; m++) {
            acc1[m] = (f32x4){0.0f, 0.0f, 0.0f, 0.0f};
            acc2[m] = (f32x4){0.0f, 0.0f, 0.0f, 0.0f};
        }

#pragma unroll
        for (int kk = 0; kk < KSLW / 32; kk++) {
            const int ko = kk * 32;
            short8b wh  = *(const short8b*)(Whi  + bof + ko);   // cached, L2-hot
            short8b wl  = *(const short8b*)(Wlo  + bof + ko);
            short8b w2h = *(const short8b*)(W2hi + bof + ko);
            short8b w2l = *(const short8b*)(W2lo + bof + ko);
            short8b ah[MFR], al[MFR];
#pragma unroll
            for (int m = 0; m < MFR; m++) {
                ah[m] = load16_sc1(rin_hi + aofm[m] + ko);      // coherent 16B
                al[m] = load16_sc1(rin_lo + aofm[m] + ko);
            }
            asm volatile("s_waitcnt vmcnt(0)" ::: "memory");
            __builtin_amdgcn_sched_barrier(0);
#pragma unroll
            for (int m = 0; m < MFR; m++) {
                // identical pass set to rounds 4/5/7 (numerics held constant)
                acc1[m] = __builtin_amdgcn_mfma_f32_16x16x32_bf16(ah[m], wh,  acc1[m], 0, 0, 0);
                acc1[m] = __builtin_amdgcn_mfma_f32_16x16x32_bf16(ah[m], wl,  acc1[m], 0, 0, 0);
                acc1[m] = __builtin_amdgcn_mfma_f32_16x16x32_bf16(al[m], wh,  acc1[m], 0, 0, 0);
                acc2[m] = __builtin_amdgcn_mfma_f32_16x16x32_bf16(ah[m], w2h, acc2[m], 0, 0, 0);
                acc2[m] = __builtin_amdgcn_mfma_f32_16x16x32_bf16(ah[m], w2l, acc2[m], 0, 0, 0);
                acc2[m] = __builtin_amdgcn_mfma_f32_16x16x32_bf16(al[m], w2h, acc2[m], 0, 0, 0);
            }
        }

        // ---- dump accs to own slot; C/D map: col(i)=lr, row(b in frag)=4*lq+r
        {
            float* sp = sm + wave * SLOTF;
#pragma unroll
            for (int m = 0; m < MFR; m++) {
                float* p1 = sp + lr * BP + m * 16 + 4 * lq;
                float* p2 = p1 + 16 * BP;
                *(f32x4*)p1 = acc1[m];
                *(f32x4*)p2 = acc2[m];
            }
        }
        __syncthreads();

        // ---- sum 16 slots + phi + Euler; pack pairs; coherent stores --------
        if (upd) {
            float rn = 0.0f;
            if (ig < NN) {
                float u1 = 0.0f, u2 = 0.0f;
#pragma unroll
                for (int w = 0; w < WAVES; w++) {
                    u1 += sm[w * SLOTF + c * BP + bb];
                    u2 += sm[w * SLOTF + (16 + c) * BP + bb];
                }
                float mu = 0.01f * u1 + mean0;
                float sg = sqrtf(0.01f * u2 + 25.0f);      // SIG_EXT^2 = 25
                float tr = (ig < NEE) ? 0.005f : 0.001f;
                float Ti = (ig < NEE) ? 100.0f : 200.0f;
                float ph = phi_lif(mu, sg, 0.01f, tr);
                rr = rr + 1e-3f * Ti * (ph - rr);
                rn = rr;
                if (s == NSTEP - 1) out[(size_t)ig * BATCH + gb] = rn;
            }
            int hh = (int)bf16_rn(rn);
            int ll = (int)bf16_rn(rn - bf16f((ushort)hh));
            int hN = __shfl_down(hh, 1);   // neighbor c+1 (same wave, even c)
            int lN = __shfl_down(ll, 1);
            if ((c & 1) == 0) {
                uint hp = (uint)hh | ((uint)hN << 16);
                uint lp = (uint)ll | ((uint)lN << 16);
                __hip_atomic_store((uint*)(rout_hi + gx), hp,
                                   __ATOMIC_RELAXED, __HIP_MEMORY_SCOPE_AGENT);
                __hip_atomic_store((uint*)(rout_lo + gx), lp,
                                   __ATOMIC_RELAXED, __HIP_MEMORY_SCOPE_AGENT);
            }
        }

        // ---- hierarchical group barrier ------------------------------------
        // __syncthreads drains vmcnt (all WG stores at coherence point), then
        // leader: sub-counter (12 arrivals) -> master (8) -> broadcast flag.
        __syncthreads();
        if (tid == 0) {
            const int g = bx & 7;
            uint* sub = cnt + (size_t)(bhf * 8 + g) * 32;   // 128B-separated lines
            uint* mst = cnt + (size_t)(16 + bhf) * 32;
            uint* flg = cnt + (size_t)(18 + bhf) * 32;
            const uint sv = (uint)(s + 1);
            uint old = __hip_atomic_fetch_add(sub, 1u,
                           __ATOMIC_RELAXED, __HIP_MEMORY_SCOPE_AGENT);
            if (old == sv * SUBWG - 1u) {
                uint mo = __hip_atomic_fetch_add(mst, 1u,
                              __ATOMIC_RELAXED, __HIP_MEMORY_SCOPE_AGENT);
                if (mo == sv * 8u - 1u) {
                    __hip_atomic_store(flg, sv,
                        __ATOMIC_RELAXED, __HIP_MEMORY_SCOPE_AGENT);
                } else {
                    while (__hip_atomic_load(flg, __ATOMIC_RELAXED,
                               __HIP_MEMORY_SCOPE_AGENT) < sv)
                        __builtin_amdgcn_s_sleep(1);
                }
            } else {
                while (__hip_atomic_load(flg, __ATOMIC_RELAXED,
                           __HIP_MEMORY_SCOPE_AGENT) < sv)
                    __builtin_amdgcn_s_sleep(1);
            }
        }
        __syncthreads();                    // release whole WG into next step
    }
}

// ---------------- launch ----------------------------------------------------

extern "C" void kernel_launch(void* const* d_in, const int* in_sizes, int n_in,
                              void* d_out, int out_size, void* d_ws, size_t ws_size,
                              hipStream_t stream) {
    const float* hyp      = (const float*)d_in[0];   // [3][4]
    const float* rand_mat = (const float*)d_in[1];   // [1500][1500]
    float* out            = (float*)d_out;           // [1500][8][12]

    char* p = (char*)d_ws;
    ushort* Whi  = (ushort*)p; p += (size_t)NPAD * NPAD * 2;
    ushort* Wlo  = (ushort*)p; p += (size_t)NPAD * NPAD * 2;
    ushort* W2hi = (ushort*)p; p += (size_t)NPAD * NPAD * 2;
    ushort* W2lo = (ushort*)p; p += (size_t)NPAD * NPAD * 2;
    ushort* rhiA = (ushort*)p; p += (size_t)BATCH * NPAD * 2;
    ushort* rloA = (ushort*)p; p += (size_t)BATCH * NPAD * 2;
    ushort* rhiB = (ushort*)p; p += (size_t)BATCH * NPAD * 2;
    ushort* rloB = (ushort*)p; p += (size_t)BATCH * NPAD * 2;
    uint*   cnt  = (uint*)p;   p += 4096;

    hipFuncSetAttribute((const void*)k_coop,
                        hipFuncAttributeMaxDynamicSharedMemorySize, LDS_BYTES);

    k_weights<<<dim3(NPAD / 256, NPAD), 256, 0, stream>>>(hyp, rand_mat,
                                                          Whi, Wlo, W2hi, W2lo);
    k_init<<<dim3(NPAD / 256, BATCH), 256, 0, stream>>>(rhiA, rloA, cnt);

    void* args[] = {(void*)&Whi, (void*)&Wlo, (void*)&W2hi, (void*)&W2lo,
                    (void*)&rhiA, (void*)&rloA, (void*)&rhiB, (void*)&rloB,
                    (void*)&cnt, (void*)&out};
    hipLaunchCooperativeKernel((const void*)k_coop, dim3(NWG), dim3(NTHR),
                               args, LDS_BYTES, stream);
}